// Round 14
// baseline (124.955 us; speedup 1.0000x reference)
//
#include <hip/hip_runtime.h>
#include <hip/hip_bf16.h>

#define NB 16
#define NC 128
#define NN 2048
#define NF 64
#define NEG_SLOPE 0.33f
#define EXP_K 1.4426950408889634f   // log2(e): pre-scale so exp() is exp2()

typedef float    f32x2 __attribute__((ext_vector_type(2)));
typedef float    f32x4 __attribute__((ext_vector_type(4)));
typedef _Float16 f16x2 __attribute__((ext_vector_type(2)));
typedef _Float16 f16x4 __attribute__((ext_vector_type(4)));
typedef _Float16 f16x8 __attribute__((ext_vector_type(8)));

__device__ __forceinline__ float lrelu(float x) {
    return fmaxf(x, x * NEG_SLOPE);   // valid leaky-relu for slope<1; commutes with positive scaling
}

// Kernel 1: Wh = h^T @ W in fp32 (VALU, LDS-tiled); emit WhT f16 [b][f][n],
// s1 = Wh@a1, s2 = Wh@a2 in fp32.  (unchanged)
__global__ __launch_bounds__(256) void k_precompute(
    const float* __restrict__ h, const float* __restrict__ W,
    const float* __restrict__ a, _Float16* __restrict__ wht,
    float* __restrict__ s1g, float* __restrict__ s2g)
{
    __shared__ float Wl[64 * 64];
    __shared__ float ht[64 * 129];

    const int t = threadIdx.x;
    const int b = blockIdx.x >> 5;
    const int n0 = (blockIdx.x & 31) << 6;
    const int lane = t & 63, cg = t >> 6;

    #pragma unroll 8
    for (int k = 0; k < 32; ++k) {
        const int c = cg * 32 + k;
        ht[lane * 129 + c] = h[(size_t)(b * NC + c) * NN + n0 + lane];
    }

    const int fg = t & 15, ns = t >> 4;
    f32x4 acc[4] = {};
    for (int half = 0; half < 2; ++half) {
        if (half) __syncthreads();
        #pragma unroll
        for (int k = 0; k < 4; ++k) {
            const int idx = k * 1024 + t * 4;
            *(f32x4*)&Wl[idx] = *(const f32x4*)&W[half * 4096 + idx];
        }
        __syncthreads();
        #pragma unroll 4
        for (int c2 = 0; c2 < 64; ++c2) {
            const f32x4 wv = *(const f32x4*)&Wl[c2 * 64 + fg * 4];
            #pragma unroll
            for (int m = 0; m < 4; ++m) {
                const float hv = ht[(ns * 4 + m) * 129 + half * 64 + c2];
                acc[m] += wv * hv;
            }
        }
    }

    const f32x4 a1v = *(const f32x4*)&a[fg * 4];
    const f32x4 a2v = *(const f32x4*)&a[NF + fg * 4];
    #pragma unroll
    for (int m = 0; m < 4; ++m) {
        float p1 = acc[m].x * a1v.x + acc[m].y * a1v.y + acc[m].z * a1v.z + acc[m].w * a1v.w;
        float p2 = acc[m].x * a2v.x + acc[m].y * a2v.y + acc[m].z * a2v.z + acc[m].w * a2v.w;
        #pragma unroll
        for (int d = 1; d < 16; d <<= 1) {
            p1 += __shfl_xor(p1, d, 64);
            p2 += __shfl_xor(p2, d, 64);
        }
        if (fg == 0) {
            const int n = n0 + ns * 4 + m;
            s1g[(size_t)b * NN + n] = p1;
            s2g[(size_t)b * NN + n] = p2;
        }
    }
    #pragma unroll
    for (int q = 0; q < 4; ++q) {
        f16x4 v;
        v[0] = (_Float16)acc[0][q]; v[1] = (_Float16)acc[1][q];
        v[2] = (_Float16)acc[2][q]; v[3] = (_Float16)acc[3][q];
        const int f = fg * 4 + q;
        *(f16x4*)&wht[((size_t)b * NF + f) * NN + n0 + ns * 4] = v;
    }
}

// Kernel 1b: fillBuffer-clone mask stream.  g (268 MB) -> mask bytes (8 MB).
// Layout: maskB[row*256 + byt], bit j of byt = (g[row][byt*8 + j] > 0).
// Block handles one full 8 KB row per iteration (thread t: 32 B at col t*8 ->
// exactly one mask byte -> coalesced byte store). 2048 blocks x 16 iters
// covers all 32768 rows exactly. ~16 VGPR -> 32 waves/CU; unroll 4 -> 8
// dwordx4 loads in flight per lane. Pure linear stream, fillBuffer-class.
#define KM_BLOCKS 2048
__global__ __launch_bounds__(256) void k_mask(
    const float* __restrict__ g, unsigned char* __restrict__ maskB)
{
    const int t = threadIdx.x;
    #pragma unroll 4
    for (int it = 0; it < (NB * NN) / KM_BLOCKS; ++it) {
        const int row = blockIdx.x + it * KM_BLOCKS;
        const float* rp = g + (size_t)row * NN + t * 8;
        const f32x4 va = *(const f32x4*)rp;
        const f32x4 vb = *(const f32x4*)(rp + 4);
        unsigned m = 0;
        m |= (va.x > 0.0f) ? 1u   : 0u;
        m |= (va.y > 0.0f) ? 2u   : 0u;
        m |= (va.z > 0.0f) ? 4u   : 0u;
        m |= (va.w > 0.0f) ? 8u   : 0u;
        m |= (vb.x > 0.0f) ? 16u  : 0u;
        m |= (vb.y > 0.0f) ? 32u  : 0u;
        m |= (vb.z > 0.0f) ? 64u  : 0u;
        m |= (vb.w > 0.0f) ? 128u : 0u;
        maskB[(size_t)row * 256 + t] = (unsigned char)m;
    }
}

// Kernel 2: mask-driven flash-GAT (ZERO HBM-g in the hot loop).
// Block = 4 waves: 2 row-groups x 2 j-halves; wave = 16 rows x 1024 cols,
// 16 chunks of 64. Prologue stages the block's 8 KB mask slice into LDS
// (stride 272: 16B-aligned rows, 4-bank offset). Per chunk: 8 bf (wht, L2)
// loads; P-gen from mask bytes + fixed bound-shift exp2 -> wave-private
// swizzled Pc; 2x ds_read_b128 A-frags; 10 MFMA (ones-MFMA = exact row sums).
//
// GRID CONTRACT (R4/R7 bug class): decode is p = (hi<<9)|(strip<<3)|xcd with
// hi in [0,2), strip in [0,64), xcd in [0,8)  ==> grid MUST be 2*64*8 = 1024.
#define K2_N_HI    2
#define K2_N_STRIP 64
#define K2_N_XCD   8
#define MBL_STRIDE 272            // bytes; 16-aligned, 68 dwords -> +4 banks/row
__global__ __launch_bounds__(256) void k_attn(
    const unsigned char* __restrict__ maskB, const _Float16* __restrict__ wht,
    const float* __restrict__ s1g, const float* __restrict__ s2g,
    float* __restrict__ out)
{
    __shared__ float s2b[NN];                        // 8 KB (pre-scaled by log2 e)
    __shared__ float s1b[32];
    __shared__ float wred[4];
    __shared__ __align__(16) unsigned char mbl[32 * MBL_STRIDE];  // 8.5 KB mask slice
    __shared__ __align__(16) _Float16 Pc[4][1024];   // per-wave 16 rows x 64 f16
    __shared__ f32x4 accS[2][5][64];                 // jq=1 partials: [rg][acc0..3,sums][lane]

    const int t = threadIdx.x;
    const int lane = t & 63;
    const int w = t >> 6;                            // wave 0..3
    const int rg = w & 1, jq = w >> 1;               // row-group, j-half

    // XCD-pinned decode (bijective over the 1024-block grid)
    const int p = blockIdx.x;
    const int b = (p & 7) + ((p >> 9) << 3);
    const int strip = (p >> 3) & 63;
    const int i0 = strip * 32;                       // block's first row
    const int iw = i0 + rg * 16;                     // wave's first row

    // ---- prologue: scaled s2 -> LDS, s1 tile, mask slice -> LDS, block max(s2) ----
    f32x4 sA = *(const f32x4*)&s2g[(size_t)b * NN + t * 8];
    f32x4 sB = *(const f32x4*)&s2g[(size_t)b * NN + t * 8 + 4];
    sA *= EXP_K; sB *= EXP_K;
    *(f32x4*)&s2b[t * 8] = sA;
    *(f32x4*)&s2b[t * 8 + 4] = sB;
    if (t < 32) s1b[t] = s1g[(size_t)b * NN + i0 + t] * EXP_K;
    {   // stage 32 rows x 256 B of mask: thread t -> row t>>3, 32 B chunk (t&7)*32
        const int mr = t >> 3, mc = (t & 7) * 32;
        const float* src = (const float*)(maskB + (size_t)(b * NN + i0 + mr) * 256 + mc);
        f32x4 v0 = *(const f32x4*)src;
        f32x4 v1 = *(const f32x4*)(src + 4);
        *(f32x4*)&mbl[mr * MBL_STRIDE + mc]      = v0;
        *(f32x4*)&mbl[mr * MBL_STRIDE + mc + 16] = v1;
    }
    float lm = fmaxf(fmaxf(fmaxf(sA.x, sA.y), fmaxf(sA.z, sA.w)),
                     fmaxf(fmaxf(sB.x, sB.y), fmaxf(sB.z, sB.w)));
    #pragma unroll
    for (int d = 1; d < 64; d <<= 1) lm = fmaxf(lm, __shfl_xor(lm, d, 64));
    if (lane == 0) wred[w] = lm;
    __syncthreads();
    const float S2MAX = fmaxf(fmaxf(wred[0], wred[1]), fmaxf(wred[2], wred[3]));

    // per-lane row constants (VGPRs, statically indexed by u — rule #20)
    const int rh = lane >> 5;                        // row parity handled by this lane
    const int cp = lane & 31;                        // col-pair index
    float s1u[8], Mu[8];
    #pragma unroll
    for (int u = 0; u < 8; ++u) {
        const float v = s1b[rg * 16 + u * 2 + rh];
        s1u[u] = v;
        Mu[u]  = lrelu(v + S2MAX);                   // scaled upper bound on row scores
    }

    const int fc = lane & 15, kg = lane >> 4;
    const _Float16* wb = wht + ((size_t)b * NF + fc) * NN + jq * 1024 + kg * 8;
    char* pcb = (char*)&Pc[w][0];
    // mask byte address pieces: row (rg*16+u*2+rh), byte jq*128 + ch*8 + (cp>>2)
    const unsigned char* mbase = &mbl[(rg * 16 + rh) * MBL_STRIDE + jq * 128 + (cp >> 2)];
    const unsigned sh = (cp & 3) * 2;                // bit position of col cp*2 within byte

    f32x4 acc0 = {0,0,0,0}, acc1 = {0,0,0,0}, acc2 = {0,0,0,0}, acc3 = {0,0,0,0};
    f32x4 acc_s = {0,0,0,0};                         // exact row sums via ones-MFMA
    f16x8 ones;
    #pragma unroll
    for (int u = 0; u < 8; ++u) ones[u] = (_Float16)1.0f;

    #pragma unroll 1
    for (int ch = 0; ch < 16; ++ch) {
        // [1] wht B-frags for this chunk (L2-resident; latency hides under P-gen)
        f16x8 bfv[2][4];
        #pragma unroll
        for (int ks = 0; ks < 2; ++ks) {
            #pragma unroll
            for (int ft = 0; ft < 4; ++ft)
                bfv[ks][ft] = *(const f16x8*)(wb + (size_t)ft * 16 * NN + ch * 64 + ks * 32);
        }
        // [2] P-gen from LDS mask bytes (no HBM): exp2 with fixed bound shift
        const f32x2 sv = *(const f32x2*)&s2b[jq * 1024 + ch * 64 + cp * 2];
        #pragma unroll
        for (int u = 0; u < 8; ++u) {
            const int row = u * 2 + rh;
            const unsigned bits = (unsigned)mbase[u * 2 * MBL_STRIDE + ch * 8] >> sh;
            const float p0 = (bits & 1u)
                ? __builtin_amdgcn_exp2f(lrelu(s1u[u] + sv.x) - Mu[u]) : 0.0f;
            const float p1 = (bits & 2u)
                ? __builtin_amdgcn_exp2f(lrelu(s1u[u] + sv.y) - Mu[u]) : 0.0f;
            f16x2 pv; pv[0] = (_Float16)p0; pv[1] = (_Float16)p1;
            *(f16x2*)(pcb + ((row * 128 + cp * 4) ^ ((row & 7) << 4))) = pv;
        }
        // [3] A-frags (same-wave lgkmcnt ordering; no barrier) + 10 MFMA
        #pragma unroll
        for (int ks = 0; ks < 2; ++ks) {
            const f16x8 af = *(const f16x8*)(pcb +
                ((fc * 128 + ks * 64 + kg * 16) ^ ((fc & 7) << 4)));
            acc0  = __builtin_amdgcn_mfma_f32_16x16x32_f16(af, bfv[ks][0], acc0, 0, 0, 0);
            acc1  = __builtin_amdgcn_mfma_f32_16x16x32_f16(af, bfv[ks][1], acc1, 0, 0, 0);
            acc2  = __builtin_amdgcn_mfma_f32_16x16x32_f16(af, bfv[ks][2], acc2, 0, 0, 0);
            acc3  = __builtin_amdgcn_mfma_f32_16x16x32_f16(af, bfv[ks][3], acc3, 0, 0, 0);
            acc_s = __builtin_amdgcn_mfma_f32_16x16x32_f16(af, ones,       acc_s, 0, 0, 0);
        }
    }

    // ---- epilogue: combine j-half partials (additive under fixed shift), normalize, store ----
    if (jq == 1) {
        accS[rg][0][lane] = acc0;
        accS[rg][1][lane] = acc1;
        accS[rg][2][lane] = acc2;
        accS[rg][3][lane] = acc3;
        accS[rg][4][lane] = acc_s;
    }
    __syncthreads();
    if (jq == 0) {
        acc0  += accS[rg][0][lane];
        acc1  += accS[rg][1][lane];
        acc2  += accS[rg][2][lane];
        acc3  += accS[rg][3][lane];
        acc_s += accS[rg][4][lane];
        f32x4 rinv;
        #pragma unroll
        for (int q = 0; q < 4; ++q) rinv[q] = 1.0f / acc_s[q];

        const size_t ob = ((size_t)b * NF + fc) * NN + (size_t)iw + kg * 4;
        f32x4 o0, o1, o2, o3;
        #pragma unroll
        for (int q = 0; q < 4; ++q) {    // D row m = kg*4+q (m89-verified), col = fc
            o0[q] = acc0[q] * rinv[q];
            o1[q] = acc1[q] * rinv[q];
            o2[q] = acc2[q] * rinv[q];
            o3[q] = acc3[q] * rinv[q];
        }
        *(f32x4*)&out[ob]                   = o0;
        *(f32x4*)&out[ob + (size_t)16 * NN] = o1;
        *(f32x4*)&out[ob + (size_t)32 * NN] = o2;
        *(f32x4*)&out[ob + (size_t)48 * NN] = o3;
    }
}

extern "C" void kernel_launch(void* const* d_in, const int* in_sizes, int n_in,
                              void* d_out, int out_size, void* d_ws, size_t ws_size,
                              hipStream_t stream)
{
    (void)in_sizes; (void)n_in; (void)out_size; (void)ws_size;
    const float* h = (const float*)d_in[0];
    const float* g = (const float*)d_in[1];
    const float* W = (const float*)d_in[2];
    const float* a = (const float*)d_in[3];
    float* out = (float*)d_out;

    // workspace: WhT f16 (4 MiB) | s1 (128 KiB) | s2 (128 KiB) | maskB (8 MiB)
    char* ws = (char*)d_ws;
    _Float16* wht = (_Float16*)ws;
    float* s1 = (float*)(ws + (size_t)NB * NF * NN * sizeof(_Float16));
    float* s2 = s1 + (size_t)NB * NN;
    unsigned char* maskB = (unsigned char*)(s2 + (size_t)NB * NN);

    k_mask<<<KM_BLOCKS, 256, 0, stream>>>(g, maskB);               // linear stream
    k_precompute<<<NB * (NN / 64), 256, 0, stream>>>(h, W, a, wht, s1, s2);
    // grid derived from the decode's factor sizes — R4/R7 bug class guard
    k_attn<<<K2_N_HI * K2_N_STRIP * K2_N_XCD, 256, 0, stream>>>(maskB, wht, s1, s2, out);
}